// Round 1
// baseline (1941.465 us; speedup 1.0000x reference)
//
#include <hip/hip_runtime.h>
#include <hip/hip_bf16.h>
#include <math.h>

#define D64 64

// ---------------- setup kernels ----------------

__global__ void zero_int_kernel(int* __restrict__ p, int n) {
    int i = blockIdx.x * blockDim.x + threadIdx.x;
    int s = gridDim.x * blockDim.x;
    for (; i < n; i += s) p[i] = 0;
}

__global__ void count_kernel(const int* __restrict__ dst, int* __restrict__ cnt, int E) {
    int e = blockIdx.x * blockDim.x + threadIdx.x;
    if (e < E) atomicAdd(&cnt[dst[e]], 1);
}

// single-block exclusive scan of cnt[0..n) -> off[0..n]
__global__ __launch_bounds__(1024)
void scan_kernel(const int* __restrict__ cnt, int* __restrict__ off, int n) {
    __shared__ int wsum[16];
    __shared__ int carry;
    int tid = threadIdx.x, lane = tid & 63, wid = tid >> 6;
    if (tid == 0) carry = 0;
    __syncthreads();
    for (int base = 0; base < n; base += 1024) {
        int i = base + tid;
        int v = (i < n) ? cnt[i] : 0;
        int sc = v;
        #pragma unroll
        for (int s = 1; s < 64; s <<= 1) {
            int t = __shfl_up(sc, (unsigned)s, 64);
            if (lane >= s) sc += t;
        }
        if (lane == 63) wsum[wid] = sc;
        __syncthreads();
        int woff = 0;
        for (int k = 0; k < wid; k++) woff += wsum[k];
        int inc = carry + woff + sc;   // inclusive prefix incl. carry
        if (i < n) off[i + 1] = inc;
        if (i == 0) off[0] = 0;
        __syncthreads();
        if (tid == 0) {
            int t = 0;
            for (int k = 0; k < 16; k++) t += wsum[k];
            carry += t;
        }
        __syncthreads();
    }
}

// scatter edge ids into CSR buckets; consumes cnt (leaves zeros)
__global__ void fill_kernel(const int* __restrict__ dst, const int* __restrict__ off,
                            int* __restrict__ cnt, int* __restrict__ eidx, int E) {
    int e = blockIdx.x * blockDim.x + threadIdx.x;
    if (e < E) {
        int d = dst[e];
        int pos = atomicSub(&cnt[d], 1) - 1;
        eidx[off[d] + pos] = e;
    }
}

// ---------------- tiled GEMM: C[M,64] (per group) = A[M,64] @ B[g][64,64] + epilogue ----------------
// block: 128 threads, tile 128 rows x 64 cols, 8x8 per thread.
// EDGE mode: adds bias + x3[dst] + x4[src], accumulates BN stats, writes h_e.
// node mode: adds bias, writes xp[g][row][c].

template <bool EDGE>
__global__ __launch_bounds__(128)
void gemm_kernel(const float* __restrict__ A, const float* __restrict__ Bg,
                 const float* __restrict__ bias, float* __restrict__ out,
                 const float* __restrict__ x3, const float* __restrict__ x4,
                 const int* __restrict__ dst, const int* __restrict__ src,
                 float* __restrict__ estats, int M, long long group_stride) {
    __shared__ float At[64 * 128];   // transposed A tile [k][row]
    __shared__ float Bs[64 * 64];    // B tile [k][col]
    __shared__ int dstl[128], srcl[128];

    int tid = threadIdx.x;
    int row0 = blockIdx.x * 128;
    int g = blockIdx.y;

    // stage B (contiguous 4096 floats)
    for (int i = tid * 4; i < 4096; i += 128 * 4) {
        *(float4*)&Bs[i] = *(const float4*)&Bg[(long long)g * 4096 + i];
    }
    // stage A transposed
    for (int i = tid; i < 128 * 16; i += 128) {
        int r = i >> 4, k4 = i & 15;
        int row = row0 + r;
        float4 v = make_float4(0.f, 0.f, 0.f, 0.f);
        if (row < M) v = *(const float4*)&A[(long long)row * 64 + k4 * 4];
        At[(k4 * 4 + 0) * 128 + r] = v.x;
        At[(k4 * 4 + 1) * 128 + r] = v.y;
        At[(k4 * 4 + 2) * 128 + r] = v.z;
        At[(k4 * 4 + 3) * 128 + r] = v.w;
    }
    if (EDGE) {
        // EDGE mode: M divisible by 128 (800000 = 6250*128)
        dstl[tid] = dst[row0 + tid];
        srcl[tid] = src[row0 + tid];
    }
    __syncthreads();

    int rg = tid >> 3, cg = tid & 7;
    int r0 = rg * 8, c0 = cg * 8;

    float acc[8][8];
    #pragma unroll
    for (int i = 0; i < 8; i++)
        #pragma unroll
        for (int j = 0; j < 8; j++) acc[i][j] = 0.f;

    for (int k = 0; k < 64; k++) {
        float4 a0 = *(float4*)&At[k * 128 + r0];
        float4 a1 = *(float4*)&At[k * 128 + r0 + 4];
        float4 b0 = *(float4*)&Bs[k * 64 + c0];
        float4 b1 = *(float4*)&Bs[k * 64 + c0 + 4];
        float av[8] = {a0.x, a0.y, a0.z, a0.w, a1.x, a1.y, a1.z, a1.w};
        float bv[8] = {b0.x, b0.y, b0.z, b0.w, b1.x, b1.y, b1.z, b1.w};
        #pragma unroll
        for (int i = 0; i < 8; i++)
            #pragma unroll
            for (int j = 0; j < 8; j++) acc[i][j] = fmaf(av[i], bv[j], acc[i][j]);
    }

    float bb[8];
    #pragma unroll
    for (int j = 0; j < 8; j++) bb[j] = bias[g * 64 + c0 + j];

    if (EDGE) {
        float ps[8], pq[8];
        #pragma unroll
        for (int j = 0; j < 8; j++) { ps[j] = 0.f; pq[j] = 0.f; }
        #pragma unroll
        for (int i = 0; i < 8; i++) {
            int rl = r0 + i;
            long long row = row0 + rl;
            int de = dstl[rl], se = srcl[rl];
            float4 g3a = *(const float4*)&x3[(long long)de * 64 + c0];
            float4 g3b = *(const float4*)&x3[(long long)de * 64 + c0 + 4];
            float4 g4a = *(const float4*)&x4[(long long)se * 64 + c0];
            float4 g4b = *(const float4*)&x4[(long long)se * 64 + c0 + 4];
            float xv[8] = {g3a.x + g4a.x, g3a.y + g4a.y, g3a.z + g4a.z, g3a.w + g4a.w,
                           g3b.x + g4b.x, g3b.y + g4b.y, g3b.z + g4b.z, g3b.w + g4b.w};
            float o[8];
            #pragma unroll
            for (int j = 0; j < 8; j++) {
                float h = acc[i][j] + bb[j] + xv[j];
                o[j] = h;
                ps[j] += h;
                pq[j] += h * h;
            }
            *(float4*)&out[row * 64 + c0]     = make_float4(o[0], o[1], o[2], o[3]);
            *(float4*)&out[row * 64 + c0 + 4] = make_float4(o[4], o[5], o[6], o[7]);
        }
        // block reduce stats into estats[0..63] (sum) and [64..127] (sumsq)
        __syncthreads();
        float* red = At;  // reuse: [16][64]
        #pragma unroll
        for (int j = 0; j < 8; j++) red[rg * 64 + c0 + j] = ps[j];
        __syncthreads();
        if (tid < 64) {
            float s = 0.f;
            #pragma unroll
            for (int r = 0; r < 16; r++) s += red[r * 64 + tid];
            atomicAdd(&estats[tid], s);
        }
        __syncthreads();
        #pragma unroll
        for (int j = 0; j < 8; j++) red[rg * 64 + c0 + j] = pq[j];
        __syncthreads();
        if (tid < 64) {
            float s = 0.f;
            #pragma unroll
            for (int r = 0; r < 16; r++) s += red[r * 64 + tid];
            atomicAdd(&estats[64 + tid], s);
        }
    } else {
        #pragma unroll
        for (int i = 0; i < 8; i++) {
            int row = row0 + r0 + i;
            if (row < M) {
                float* op = out + (long long)g * group_stride + (long long)row * 64 + c0;
                *(float4*)op       = make_float4(acc[i][0] + bb[0], acc[i][1] + bb[1],
                                                 acc[i][2] + bb[2], acc[i][3] + bb[3]);
                *(float4*)(op + 4) = make_float4(acc[i][4] + bb[4], acc[i][5] + bb[5],
                                                 acc[i][6] + bb[6], acc[i][7] + bb[7]);
            }
        }
    }
}

// ---------------- CSR mean aggregation + h_v + node BN partial stats ----------------
// one wave per node, lane = feature d
__global__ __launch_bounds__(256)
void agg_kernel(const float* __restrict__ w, const float* __restrict__ x1,
                const float* __restrict__ x2, const int* __restrict__ off,
                const int* __restrict__ eidx, const int* __restrict__ src,
                float* __restrict__ h_v, float* __restrict__ nstats, int Nn) {
    int lane = threadIdx.x & 63;
    int wid = threadIdx.x >> 6;
    int gw = blockIdx.x * 4 + wid;
    int nw = gridDim.x * 4;
    float sp = 0.f, sq = 0.f;
    for (int n = gw; n < Nn; n += nw) {
        int o0 = off[n], o1 = off[n + 1];
        float acc = 0.f;
        if (o0 < o1) {
            int e = eidx[o0];
            int s = src[e];
            for (int j = o0; j < o1; j++) {
                int en = 0, sn = 0;
                if (j + 1 < o1) { en = eidx[j + 1]; sn = src[en]; }
                float wv = w[(long long)e * 64 + lane];
                float xv = x2[(long long)s * 64 + lane];
                acc += xv / (1.f + __expf(-wv));   // sigmoid(w)*x2
                e = en; s = sn;
            }
        }
        float cntf = (float)(o1 - o0);
        float h = x1[(long long)n * 64 + lane] + acc / fmaxf(cntf, 1.f);
        h_v[(long long)n * 64 + lane] = h;
        sp += h;
        sq += h * h;
    }
    __shared__ float red[4][64];
    red[wid][lane] = sp;
    __syncthreads();
    if (threadIdx.x < 64) {
        float s = red[0][threadIdx.x] + red[1][threadIdx.x] + red[2][threadIdx.x] + red[3][threadIdx.x];
        atomicAdd(&nstats[threadIdx.x], s);
    }
    __syncthreads();
    red[wid][lane] = sq;
    __syncthreads();
    if (threadIdx.x < 64) {
        float s = red[0][threadIdx.x] + red[1][threadIdx.x] + red[2][threadIdx.x] + red[3][threadIdx.x];
        atomicAdd(&nstats[64 + threadIdx.x], s);
    }
}

// ---------------- BN + SiLU + residual (elementwise, float4) ----------------
__global__ __launch_bounds__(256)
void bn_silu_kernel(const float4* __restrict__ h, const float4* __restrict__ xold,
                    float4* __restrict__ xnew, const float* __restrict__ stats,
                    const float* __restrict__ scale, const float* __restrict__ bias,
                    float invCnt, int total4) {
    int idx = blockIdx.x * blockDim.x + threadIdx.x;
    int stride = gridDim.x * blockDim.x;
    for (; idx < total4; idx += stride) {
        int d0 = (idx & 15) * 4;
        float4 hv4 = h[idx];
        float4 xo4 = xold[idx];
        const float* hv = (const float*)&hv4;
        const float* xo = (const float*)&xo4;
        float o[4];
        #pragma unroll
        for (int j = 0; j < 4; j++) {
            int d = d0 + j;
            float mean = stats[d] * invCnt;
            float var = stats[64 + d] * invCnt - mean * mean;
            float inv = rsqrtf(var + 1e-5f);
            float gv = (hv[j] - mean) * inv * scale[d] + bias[d];
            float si = gv / (1.f + __expf(-gv));
            o[j] = xo[j] + si;
        }
        xnew[idx] = make_float4(o[0], o[1], o[2], o[3]);
    }
}

// ---------------- launch ----------------

extern "C" void kernel_launch(void* const* d_in, const int* in_sizes, int n_in,
                              void* d_out, int out_size, void* d_ws, size_t ws_size,
                              hipStream_t stream) {
    const float* x_in  = (const float*)d_in[0];
    const float* ea_in = (const float*)d_in[1];
    const int*   ei    = (const int*)d_in[2];
    const float* v_w   = (const float*)d_in[3];
    const float* v_b   = (const float*)d_in[4];
    const float* e_w   = (const float*)d_in[5];
    const float* e_b   = (const float*)d_in[6];
    const float* vbn_s = (const float*)d_in[7];
    const float* vbn_b = (const float*)d_in[8];
    const float* ebn_s = (const float*)d_in[9];
    const float* ebn_b = (const float*)d_in[10];

    const int Nn = in_sizes[0] / D64;
    const int E  = in_sizes[1] / D64;
    const int L  = in_sizes[3] / (4 * D64 * D64);

    const int* dst = ei;       // edge_index[0]
    const int* src = ei + E;   // edge_index[1]

    // workspace layout
    float* xp     = (float*)d_ws;                       // [4][Nn][64]
    float* h_v    = xp + (long long)4 * Nn * 64;        // [Nn][64]
    float* h_e    = h_v + (long long)Nn * 64;           // [E][64]
    float* nstats = h_e + (long long)E * 64;            // [L][128]
    float* estats = nstats + (long long)L * 128;        // [L][128]
    int*   cnt    = (int*)(estats + (long long)L * 128);// [Nn]
    int*   off    = cnt + Nn;                            // [Nn+1]
    int*   eidx   = off + Nn + 1;                        // [E]

    size_t needed = ((size_t)4 * Nn * 64 + (size_t)Nn * 64 + (size_t)E * 64 +
                     (size_t)L * 256) * 4 +
                    ((size_t)Nn + (size_t)Nn + 1 + (size_t)E) * 4;
    if (ws_size < needed) return;  // cannot run safely

    float* out_x = (float*)d_out;
    float* out_w = out_x + (long long)Nn * 64;

    // --- CSR build (per call; inputs constant so result deterministic up to order) ---
    zero_int_kernel<<<256, 256, 0, stream>>>(cnt, Nn);
    zero_int_kernel<<<8, 256, 0, stream>>>((int*)nstats, L * 256);  // nstats+estats contiguous
    count_kernel<<<(E + 255) / 256, 256, 0, stream>>>(dst, cnt, E);
    scan_kernel<<<1, 1024, 0, stream>>>(cnt, off, Nn);
    fill_kernel<<<(E + 255) / 256, 256, 0, stream>>>(dst, off, cnt, eidx, E);

    for (int l = 0; l < L; l++) {
        const float* xl = (l == 0) ? x_in : out_x;
        const float* wl = (l == 0) ? ea_in : out_w;

        // node projections: xp[4][Nn][64]
        gemm_kernel<false><<<dim3((Nn + 127) / 128, 4), 128, 0, stream>>>(
            xl, v_w + (long long)l * 4 * 4096, v_b + l * 256, xp,
            nullptr, nullptr, nullptr, nullptr, nullptr, Nn, (long long)Nn * 64);

        // gated mean aggregation + h_v + node BN stats
        agg_kernel<<<2048, 256, 0, stream>>>(
            wl, xp, xp + (long long)Nn * 64, off, eidx, src,
            h_v, nstats + l * 128, Nn);

        // node BN + SiLU + residual -> out_x
        bn_silu_kernel<<<1024, 256, 0, stream>>>(
            (const float4*)h_v, (const float4*)xl, (float4*)out_x,
            nstats + l * 128, vbn_s + l * 64, vbn_b + l * 64,
            1.f / (float)Nn, Nn * 16);

        // edge GEMM + gathers + edge BN stats -> h_e
        gemm_kernel<true><<<dim3((E + 127) / 128, 1), 128, 0, stream>>>(
            wl, e_w + (long long)l * 4096, e_b + l * 64, h_e,
            xp + (long long)2 * Nn * 64, xp + (long long)3 * Nn * 64,
            dst, src, estats + l * 128, E, 0);

        // edge BN + SiLU + residual -> out_w
        bn_silu_kernel<<<2048, 256, 0, stream>>>(
            (const float4*)h_e, (const float4*)wl, (float4*)out_w,
            estats + l * 128, ebn_s + l * 64, ebn_b + l * 64,
            1.f / (float)E, E * 16);
    }
}